// Round 1
// baseline (233.966 us; speedup 1.0000x reference)
//
#include <hip/hip_runtime.h>
#include <hip/hip_bf16.h>

typedef __bf16          bf16x8_t __attribute__((ext_vector_type(8)));
typedef float           f32x4_t  __attribute__((ext_vector_type(4)));
typedef unsigned short  u16x4_t  __attribute__((ext_vector_type(4)));

#define DIN      256
#define CONDN    128
#define BM       64
#define NTHREADS 512
#define NWAVE    8
#define LDA      136   // cond LDS row stride (bf16 elems): 272 B -> bank step 4, 2-way only
#define LDH      520   // h LDS row stride: 1040 B -> bank step 4, 2-way only

// d_ws bf16 layout (element offsets): W^T, i.e. [N][K] row-major, K contiguous
#define OFF_WS1 0        // [512][128]
#define OFF_WS2 65536    // [512][512]
#define OFF_WS3 327680   // [128][512]
#define OFF_WT1 393216   // [512][128]
#define OFF_WT2 458752   // [512][512]
#define OFF_WT3 720896   // [128][512]
#define W_TOTAL 786432

__global__ void prep_w(const float* __restrict__ Ws1, const float* __restrict__ Ws2,
                       const float* __restrict__ Ws3, const float* __restrict__ Wt1,
                       const float* __restrict__ Wt2, const float* __restrict__ Wt3,
                       __hip_bfloat16* __restrict__ wt) {
  int idx = blockIdx.x * blockDim.x + threadIdx.x;
  if (idx >= W_TOTAL) return;
  const float* W; int K, N, off;
  if (idx < OFF_WS2)      { W = Ws1; K = 128; N = 512; off = idx - OFF_WS1; }
  else if (idx < OFF_WS3) { W = Ws2; K = 512; N = 512; off = idx - OFF_WS2; }
  else if (idx < OFF_WT1) { W = Ws3; K = 512; N = 128; off = idx - OFF_WS3; }
  else if (idx < OFF_WT2) { W = Wt1; K = 128; N = 512; off = idx - OFF_WT1; }
  else if (idx < OFF_WT3) { W = Wt2; K = 512; N = 512; off = idx - OFF_WT2; }
  else                    { W = Wt3; K = 512; N = 128; off = idx - OFF_WT3; }
  int n = off / K;            // K is pow2 -> cheap
  int k = off - n * K;
  wt[idx] = __float2bfloat16(W[k * N + n]);   // transpose: WT[n][k] = W[k][n]
}

// One GEMM slice: out[0:64][n0:n0+16*NT] += A[0:64][0:KTOT] * W[0:KTOT][n0...]
// A in LDS (row stride lda), B = W^T rows (K contiguous) in global (L2-resident).
// k-map per lane: k = kk + 8*(lane>>4) + j  -- same bijection for A and B, so
// the contraction is correct regardless of the HW's internal k ordering.
template<int KTOT, int MT, int NT>
__device__ __forceinline__ void mm_tile(const __hip_bfloat16* __restrict__ Asrc, const int lda,
                                        const __hip_bfloat16* __restrict__ Bsrc,
                                        const int l15, const int l4, f32x4_t acc[MT][NT]) {
  #pragma unroll 4
  for (int kk = 0; kk < KTOT; kk += 32) {
    bf16x8_t a[MT], b[NT];
    #pragma unroll
    for (int m = 0; m < MT; ++m)
      a[m] = *reinterpret_cast<const bf16x8_t*>(&Asrc[(m * 16 + l15) * lda + kk + l4 * 8]);
    #pragma unroll
    for (int n = 0; n < NT; ++n)
      b[n] = *reinterpret_cast<const bf16x8_t*>(&Bsrc[(n * 16 + l15) * KTOT + kk + l4 * 8]);
    #pragma unroll
    for (int m = 0; m < MT; ++m) {
      #pragma unroll
      for (int n = 0; n < NT; ++n)
        acc[m][n] = __builtin_amdgcn_mfma_f32_16x16x32_bf16(a[m], b[n], acc[m][n], 0, 0, 0);
    }
  }
}

template<int MT, int NT>
__device__ __forceinline__ void relu_store(f32x4_t acc[MT][NT], const float* __restrict__ bias,
                                           const int n0, const int l15, const int l4,
                                           __hip_bfloat16* __restrict__ H) {
  #pragma unroll
  for (int n = 0; n < NT; ++n) {
    const float bv = bias[n0 + n * 16 + l15];
    #pragma unroll
    for (int m = 0; m < MT; ++m) {
      #pragma unroll
      for (int r = 0; r < 4; ++r) {
        float v = acc[m][n][r] + bv;
        v = fmaxf(v, 0.0f);
        H[(m * 16 + l4 * 4 + r) * LDH + n0 + n * 16 + l15] = __float2bfloat16(v);
      }
    }
  }
}

#define ZERO_ACC(acc, MT, NT) do {                       \
    _Pragma("unroll") for (int m_ = 0; m_ < MT; ++m_)    \
    _Pragma("unroll") for (int n_ = 0; n_ < NT; ++n_)    \
      acc[m_][n_] = (f32x4_t){0.f, 0.f, 0.f, 0.f};       \
  } while (0)

__global__ __launch_bounds__(NTHREADS, 2)
void realnvp_fused(const float* __restrict__ x, const __hip_bfloat16* __restrict__ wt,
                   const float* __restrict__ bs1, const float* __restrict__ bs2,
                   const float* __restrict__ bs3, const float* __restrict__ bt1,
                   const float* __restrict__ bt2, const float* __restrict__ bt3,
                   float* __restrict__ y, float* __restrict__ ld) {
  __shared__ __hip_bfloat16 sA[BM * LDA];
  __shared__ __hip_bfloat16 sH1[BM * LDH];
  __shared__ __hip_bfloat16 sH2[BM * LDH];
  __shared__ float sLd[NWAVE][BM];

  const int tid  = threadIdx.x;
  const int lane = tid & 63;
  const int wid  = tid >> 6;
  const int l15  = lane & 15;
  const int l4   = lane >> 4;
  const int row0 = blockIdx.x * BM;
  const int n0   = wid * 64;   // layer 1/2 column slice
  const int n3   = wid * 16;   // layer 3 column slice

  // ---- stage cond tile (fp32 -> bf16 LDS) and copy cond through to y (exact fp32) ----
  #pragma unroll
  for (int i = 0; i < 4; ++i) {
    int f = tid + i * NTHREADS;              // 2048 float4 chunks: 64 rows x 32
    int r = f >> 5;
    int c = (f & 31) << 2;
    const float4 v = *reinterpret_cast<const float4*>(&x[(size_t)(row0 + r) * DIN + c]);
    *reinterpret_cast<float4*>(&y[(size_t)(row0 + r) * DIN + c]) = v;
    union { u16x4_t u; __hip_bfloat16 b[4]; } p;
    p.b[0] = __float2bfloat16(v.x); p.b[1] = __float2bfloat16(v.y);
    p.b[2] = __float2bfloat16(v.z); p.b[3] = __float2bfloat16(v.w);
    *reinterpret_cast<u16x4_t*>(&sA[r * LDA + c]) = p.u;
  }
  __syncthreads();   // B1: sA ready

  f32x4_t acc[4][4];
  f32x4_t sfrag[4], tfrag[4];

  // ===================== MLP s =====================
  ZERO_ACC(acc, 4, 4);
  mm_tile<128, 4, 4>(sA, LDA, wt + OFF_WS1 + (size_t)n0 * 128, l15, l4, acc);
  relu_store<4, 4>(acc, bs1, n0, l15, l4, sH1);
  __syncthreads();   // B2: sH1 ready
  ZERO_ACC(acc, 4, 4);
  mm_tile<512, 4, 4>(sH1, LDH, wt + OFF_WS2 + (size_t)n0 * 512, l15, l4, acc);
  relu_store<4, 4>(acc, bs2, n0, l15, l4, sH2);
  __syncthreads();   // B3: sH2 ready; all sH1 reads done
  {
    f32x4_t a3[4][1];
    ZERO_ACC(a3, 4, 1);
    mm_tile<512, 4, 1>(sH2, LDH, wt + OFF_WS3 + (size_t)n3 * 512, l15, l4, a3);
    #pragma unroll
    for (int m = 0; m < 4; ++m) sfrag[m] = a3[m][0];
  }

  // ===================== MLP t =====================
  // safe to overwrite sH1: its readers (layer 2s) all passed B3
  ZERO_ACC(acc, 4, 4);
  mm_tile<128, 4, 4>(sA, LDA, wt + OFF_WT1 + (size_t)n0 * 128, l15, l4, acc);
  relu_store<4, 4>(acc, bt1, n0, l15, l4, sH1);
  __syncthreads();   // B4: sH1(t) ready; all layer-3s sH2 reads done
  ZERO_ACC(acc, 4, 4);
  mm_tile<512, 4, 4>(sH1, LDH, wt + OFF_WT2 + (size_t)n0 * 512, l15, l4, acc);
  relu_store<4, 4>(acc, bt2, n0, l15, l4, sH2);
  __syncthreads();   // B5: sH2(t) ready
  {
    f32x4_t a3[4][1];
    ZERO_ACC(a3, 4, 1);
    mm_tile<512, 4, 1>(sH2, LDH, wt + OFF_WT3 + (size_t)n3 * 512, l15, l4, a3);
    #pragma unroll
    for (int m = 0; m < 4; ++m) tfrag[m] = a3[m][0];
  }

  // ===================== epilogue =====================
  const float bsv = bs3[n3 + l15];
  const float btv = bt3[n3 + l15];
  #pragma unroll
  for (int m = 0; m < 4; ++m) {
    #pragma unroll
    for (int r = 0; r < 4; ++r) {
      const int rl   = m * 16 + l4 * 4 + r;
      const int grow = row0 + rl;
      const int col  = n3 + l15;
      float s = tanhf(sfrag[m][r] + bsv);
      float t = tfrag[m][r] + btv;
      float xv = x[(size_t)grow * DIN + CONDN + col];
      y[(size_t)grow * DIN + CONDN + col] = xv * expf(s) + t;
      // per-row partial sum of s over this wave's 16 columns
      float ss = s;
      ss += __shfl_xor(ss, 1);
      ss += __shfl_xor(ss, 2);
      ss += __shfl_xor(ss, 4);
      ss += __shfl_xor(ss, 8);
      if (l15 == 0) sLd[wid][rl] = ss;
    }
  }
  __syncthreads();   // B6: partials ready
  if (tid < BM) {
    float v = 0.f;
    #pragma unroll
    for (int w = 0; w < NWAVE; ++w) v += sLd[w][tid];
    ld[row0 + tid] = v;
  }
}

extern "C" void kernel_launch(void* const* d_in, const int* in_sizes, int n_in,
                              void* d_out, int out_size, void* d_ws, size_t ws_size,
                              hipStream_t stream) {
  const float* x   = (const float*)d_in[0];
  const float* Ws1 = (const float*)d_in[1];
  const float* bs1 = (const float*)d_in[2];
  const float* Ws2 = (const float*)d_in[3];
  const float* bs2 = (const float*)d_in[4];
  const float* Ws3 = (const float*)d_in[5];
  const float* bs3 = (const float*)d_in[6];
  const float* Wt1 = (const float*)d_in[7];
  const float* bt1 = (const float*)d_in[8];
  const float* Wt2 = (const float*)d_in[9];
  const float* bt2 = (const float*)d_in[10];
  const float* Wt3 = (const float*)d_in[11];
  const float* bt3 = (const float*)d_in[12];

  const int Btot = in_sizes[0] / DIN;          // 65536
  float* y  = (float*)d_out;
  float* ld = (float*)d_out + (size_t)Btot * DIN;
  __hip_bfloat16* wt = (__hip_bfloat16*)d_ws;  // 1.5 MB needed

  prep_w<<<(W_TOTAL + 255) / 256, 256, 0, stream>>>(Ws1, Ws2, Ws3, Wt1, Wt2, Wt3, wt);
  realnvp_fused<<<Btot / BM, NTHREADS, 0, stream>>>(x, wt, bs1, bs2, bs3,
                                                    bt1, bt2, bt3, y, ld);
}